// Round 5
// baseline (672.796 us; speedup 1.0000x reference)
//
#include <hip/hip_runtime.h>
#include <hip/hip_bf16.h>

// Fused windowed MHA (f32 I/O): LN -> QKV -> 12-head attention (+rel-pos bias LUT) -> out proj.
// prep_kernel: w_qkv/w_out f32->bf16 into d_ws, bias LUT gather (f32).
// fused kernel: one block per window (B=2048), 1024 threads = 16 waves (4/SIMD at 1 block/CU),
// 3 groups x 4 heads; all matmuls via v_mfma_f32_16x16x32_bf16 with f32 accumulation.
// Barriers: LN + 3 per group (post-GEMM2 / post-scatter / post-att). Softmax->PV and
// PV->att-write are same-wave (no barrier).

#define NTOK  64
#define CCH   384
#define NH    12
#define HD    32
#define EPSV  1e-5f
#define SCALEQ 0.17677669529663687f   // 1/sqrt(32)

#define WQKV_ELEMS (1152 * 384)
#define WOUT_ELEMS (384 * 384)
#define BLUT_ELEMS (NH * 64 * 64)

typedef __attribute__((ext_vector_type(8))) short  short8;   // 8 bf16 (A/B frag)
typedef __attribute__((ext_vector_type(4))) short  short4v;  // 4 bf16 (b64 write)
typedef __attribute__((ext_vector_type(4))) float  float4v;  // C/D frag / f32 loads

__device__ __forceinline__ unsigned short f2bf(float f) {
    union { float f; unsigned int i; } v; v.f = f;
    unsigned int r = v.i + 0x7fffu + ((v.i >> 16) & 1u);   // RNE
    return (unsigned short)(r >> 16);
}

__global__ void prep_kernel(const float* __restrict__ w_qkv_f,
                            const float* __restrict__ w_out_f,
                            const float* __restrict__ bias_tab,
                            const int*   __restrict__ rel_idx,
                            unsigned short* __restrict__ wq_bf,
                            unsigned short* __restrict__ wo_bf,
                            float* __restrict__ blut) {
    const int stride = gridDim.x * blockDim.x;
    const int tid = blockIdx.x * blockDim.x + threadIdx.x;
    for (int i = tid; i < WQKV_ELEMS; i += stride) wq_bf[i] = f2bf(w_qkv_f[i]);
    for (int i = tid; i < WOUT_ELEMS; i += stride) wo_bf[i] = f2bf(w_out_f[i]);
    for (int i = tid; i < BLUT_ELEMS; i += stride) {
        const int h = i >> 12, nm = i & 4095;              // blut[h][n][m]
        blut[i] = bias_tab[rel_idx[nm] * NH + h];
    }
}

__global__ __launch_bounds__(1024, 4)
void fused_win_mha(const float* __restrict__ x,
                   const float* __restrict__ ln_g,
                   const float* __restrict__ ln_b,
                   const float* __restrict__ b_out,
                   const unsigned short* __restrict__ w_qkv,   // bf16 [1152][384]
                   const unsigned short* __restrict__ w_out,   // bf16 [384][384]
                   const float* __restrict__ blut,             // f32 [12][64][64]
                   float* __restrict__ out)                    // f32 [B][64][384]
{
    const int b    = blockIdx.x;
    const int t    = threadIdx.x;
    const int wav  = t >> 6;        // 0..15
    const int lane = t & 63;
    const int l4   = lane >> 4;     // 0..3
    const int lc   = lane & 15;     // 0..15
    const int p    = wav >> 1;      // 0..7  GEMM N-pair
    const int mh   = wav & 1;       // 0..1  GEMM M-half
    const int hl   = wav >> 2;      // 0..3  attention head-local
    const int qr   = wav & 3;       // 0..3  attention row-quarter

    __shared__ unsigned short xn[NTOK][CCH + 8];          // 50176 B
    __shared__ unsigned short qbuf[4][NTOK][HD + 8];      // 20480 B (att overlays q)
    __shared__ unsigned short kbuf[4][NTOK][HD + 8];      // 20480 B
    __shared__ unsigned short vT[4][HD][NTOK + 8];        // 18432 B (V transposed)
    __shared__ unsigned short pbuf[4][NTOK][NTOK + 8];    // 36864 B
    // total 146432 B -> 1 block/CU, 16 waves resident

    // ---------------- LayerNorm (f32 x -> bf16 xn) ----------------
    {
        const int row = t >> 4, seg = t & 15;             // 16 threads per token row
        const float* xr = x + (b * NTOK + row) * CCH + seg * 24;
        float vals[24];
        float s = 0.f, s2 = 0.f;
        #pragma unroll
        for (int i = 0; i < 6; ++i) {
            float4v v = *(const float4v*)(xr + i * 4);
            #pragma unroll
            for (int j = 0; j < 4; ++j) {
                float f = v[j];
                vals[i * 4 + j] = f; s += f; s2 += f * f;
            }
        }
        s += __shfl_xor(s, 1); s2 += __shfl_xor(s2, 1);
        s += __shfl_xor(s, 2); s2 += __shfl_xor(s2, 2);
        s += __shfl_xor(s, 4); s2 += __shfl_xor(s2, 4);
        s += __shfl_xor(s, 8); s2 += __shfl_xor(s2, 8);
        const float mu   = s * (1.f / CCH);
        const float rstd = rsqrtf(s2 * (1.f / CCH) - mu * mu + EPSV);
        #pragma unroll
        for (int i = 0; i < 6; ++i) {
            float4v gv = *(const float4v*)(ln_g + seg * 24 + i * 4);
            float4v bv = *(const float4v*)(ln_b + seg * 24 + i * 4);
            #pragma unroll
            for (int j = 0; j < 4; ++j)
                xn[row][seg * 24 + i * 4 + j] = f2bf((vals[i * 4 + j] - mu) * rstd * gv[j] + bv[j]);
        }
    }
    __syncthreads();

    // persistent GEMM2 accumulators: [mtl 0..1][j2 0..2] -> rows 16*(2mh+mtl)+, cols 16*(3p+j2)+lc
    float4v facc[2][3];
    #pragma unroll
    for (int mtl = 0; mtl < 2; ++mtl)
        #pragma unroll
        for (int j = 0; j < 3; ++j)
            facc[mtl][j] = (float4v){0.f, 0.f, 0.f, 0.f};

    for (int grp = 0; grp < 3; ++grp) {
        // ---------------- GEMM1: qkv for heads 4g..4g+3 ----------------
        // wave (p,mh): N-tiles 3p..3p+2 (of 24), M-tiles {2mh, 2mh+1}; K=384 (12 steps)
        float4v acc[3][2];
        #pragma unroll
        for (int n = 0; n < 3; ++n)
            #pragma unroll
            for (int m = 0; m < 2; ++m)
                acc[n][m] = (float4v){0.f, 0.f, 0.f, 0.f};

        int eIdx[3], hh_[3], mat_[3], half_[3];
        #pragma unroll
        for (int ntl = 0; ntl < 3; ++ntl) {
            const int ntg = 3 * p + ntl;                   // 0..23
            const int hh = ntg / 6, p6 = ntg % 6;
            hh_[ntl] = hh; mat_[ntl] = p6 >> 1; half_[ntl] = p6 & 1;
            eIdx[ntl] = mat_[ntl] * CCH + (4 * grp + hh) * HD + half_[ntl] * 16 + lc;
        }
        for (int kk = 0; kk < 12; ++kk) {
            short8 aF[2];
            #pragma unroll
            for (int mtl = 0; mtl < 2; ++mtl)
                aF[mtl] = *(const short8*)&xn[16 * (2 * mh + mtl) + lc][32 * kk + 8 * l4];
            #pragma unroll
            for (int ntl = 0; ntl < 3; ++ntl) {
                short8 bF = *(const short8*)(w_qkv + eIdx[ntl] * CCH + 32 * kk + 8 * l4);
                #pragma unroll
                for (int mtl = 0; mtl < 2; ++mtl)
                    acc[ntl][mtl] = __builtin_amdgcn_mfma_f32_16x16x32_bf16(aF[mtl], bF, acc[ntl][mtl], 0, 0, 0);
            }
        }
        __syncthreads();   // barrier A: prev group's GEMM2 done reading qbuf(att); prev QK/PV done with kbuf/vT

        // ---------------- scatter q(scaled),k,vT to LDS ----------------
        #pragma unroll
        for (int ntl = 0; ntl < 3; ++ntl) {
            const int hh = hh_[ntl], mat = mat_[ntl], half = half_[ntl];
            #pragma unroll
            for (int mtl = 0; mtl < 2; ++mtl) {
                const int mt = 2 * mh + mtl;
                if (mat == 0) {
                    #pragma unroll
                    for (int r = 0; r < 4; ++r)
                        qbuf[hh][16 * mt + 4 * l4 + r][half * 16 + lc] = f2bf(acc[ntl][mtl][r] * SCALEQ);
                } else if (mat == 1) {
                    #pragma unroll
                    for (int r = 0; r < 4; ++r)
                        kbuf[hh][16 * mt + 4 * l4 + r][half * 16 + lc] = f2bf(acc[ntl][mtl][r]);
                } else {
                    short4v pk;
                    #pragma unroll
                    for (int r = 0; r < 4; ++r)
                        pk[r] = (short)f2bf(acc[ntl][mtl][r]);
                    *(short4v*)&vT[hh][half * 16 + lc][16 * mt + 4 * l4] = pk;  // ds_write_b64
                }
            }
        }
        __syncthreads();   // barrier B: qkv visible

        // ---------------- scores + bias + softmax (head hl, rows 16qr..16qr+15) ----------------
        const int h = 4 * grp + hl;
        float sv[4][4];   // [kt key-tile][reg]
        {
            short8 qf = *(const short8*)&qbuf[hl][16 * qr + lc][8 * l4];
            #pragma unroll
            for (int kt = 0; kt < 4; ++kt) {
                short8 kf = *(const short8*)&kbuf[hl][16 * kt + lc][8 * l4];
                float4v sres = __builtin_amdgcn_mfma_f32_16x16x32_bf16(
                    qf, kf, (float4v){0.f, 0.f, 0.f, 0.f}, 0, 0, 0);
                #pragma unroll
                for (int r = 0; r < 4; ++r) sv[kt][r] = sres[r];
            }
        }
        const float* bl = blut + h * 4096;
        float rsum[4];
        #pragma unroll
        for (int reg = 0; reg < 4; ++reg) {
            const int row = 16 * qr + 4 * l4 + reg;
            const float* blr = bl + row * 64 + lc;
            float m = -1e30f;
            #pragma unroll
            for (int kt = 0; kt < 4; ++kt) {
                sv[kt][reg] += blr[16 * kt];
                m = fmaxf(m, sv[kt][reg]);
            }
            m = fmaxf(m, __shfl_xor(m, 1));
            m = fmaxf(m, __shfl_xor(m, 2));
            m = fmaxf(m, __shfl_xor(m, 4));
            m = fmaxf(m, __shfl_xor(m, 8));
            float s = 0.f;
            #pragma unroll
            for (int kt = 0; kt < 4; ++kt) {
                float pe = __expf(sv[kt][reg] - m);
                sv[kt][reg] = pe; s += pe;
            }
            s += __shfl_xor(s, 1);
            s += __shfl_xor(s, 2);
            s += __shfl_xor(s, 4);
            s += __shfl_xor(s, 8);
            rsum[reg] = 1.f / s;
            #pragma unroll
            for (int kt = 0; kt < 4; ++kt)
                pbuf[hl][row][16 * kt + lc] = f2bf(sv[kt][reg]);   // unnormalized
        }
        // NO barrier: pbuf rows + q rows + att rows below are all same-wave; vT covered by barrier B

        // ---------------- PV (rows 16qr..16qr+15, head hl) ----------------
        float4v o[2];
        o[0] = (float4v){0.f, 0.f, 0.f, 0.f};
        o[1] = (float4v){0.f, 0.f, 0.f, 0.f};
        #pragma unroll
        for (int kk2 = 0; kk2 < 2; ++kk2) {
            short8 pf = *(const short8*)&pbuf[hl][16 * qr + lc][32 * kk2 + 8 * l4];
            #pragma unroll
            for (int nt = 0; nt < 2; ++nt) {
                short8 vf = *(const short8*)&vT[hl][16 * nt + lc][32 * kk2 + 8 * l4];
                o[nt] = __builtin_amdgcn_mfma_f32_16x16x32_bf16(pf, vf, o[nt], 0, 0, 0);
            }
        }
        // normalize rows and write att into qbuf (same-wave rows; q dead)
        #pragma unroll
        for (int nt = 0; nt < 2; ++nt)
            #pragma unroll
            for (int r = 0; r < 4; ++r)
                qbuf[hl][16 * qr + 4 * l4 + r][16 * nt + lc] = f2bf(o[nt][r] * rsum[r]);
        __syncthreads();   // barrier C: att visible

        // ---------------- GEMM2 partial: facc += att @ w_out[:, 128g..128g+127]^T ----------------
        #pragma unroll
        for (int ks = 0; ks < 4; ++ks) {       // ks = head-local index of att chunk
            short8 aG[2];
            #pragma unroll
            for (int mtl = 0; mtl < 2; ++mtl)
                aG[mtl] = *(const short8*)&qbuf[ks][16 * (2 * mh + mtl) + lc][8 * l4];
            #pragma unroll
            for (int j2 = 0; j2 < 3; ++j2) {
                const int c = 16 * (3 * p + j2) + lc;
                short8 bG = *(const short8*)(w_out + c * CCH + 128 * grp + 32 * ks + 8 * l4);
                #pragma unroll
                for (int mtl = 0; mtl < 2; ++mtl)
                    facc[mtl][j2] = __builtin_amdgcn_mfma_f32_16x16x32_bf16(aG[mtl], bG, facc[mtl][j2], 0, 0, 0);
            }
        }
        // no barrier: next group's GEMM1 reads only xn; barrier A precedes the next scatter
    }

    // ---------------- epilogue: facc + b_out -> direct f32 global stores ----------------
    {
        float* ob = out + b * (NTOK * CCH);
        #pragma unroll
        for (int mtl = 0; mtl < 2; ++mtl) {
            #pragma unroll
            for (int j2 = 0; j2 < 3; ++j2) {
                const int c = 16 * (3 * p + j2) + lc;
                const float bo = b_out[c];
                #pragma unroll
                for (int r = 0; r < 4; ++r)
                    ob[(16 * (2 * mh + mtl) + 4 * l4 + r) * CCH + c] = facc[mtl][j2][r] + bo;
            }
        }
    }
}

extern "C" void kernel_launch(void* const* d_in, const int* in_sizes, int n_in,
                              void* d_out, int out_size, void* d_ws, size_t ws_size,
                              hipStream_t stream) {
    const float* x     = (const float*)d_in[0];
    const float* ln_g  = (const float*)d_in[1];
    const float* ln_b  = (const float*)d_in[2];
    const float* w_qkv = (const float*)d_in[3];
    const float* w_out = (const float*)d_in[4];
    const float* b_out = (const float*)d_in[5];
    const float* btab  = (const float*)d_in[6];
    const int*   ridx  = (const int*)d_in[7];
    float*       out   = (float*)d_out;

    unsigned short* wq_bf = (unsigned short*)d_ws;
    unsigned short* wo_bf = wq_bf + WQKV_ELEMS;
    float*          blut  = (float*)(wo_bf + WOUT_ELEMS);   // byte offset 1179648, 16B-aligned

    prep_kernel<<<512, 256, 0, stream>>>(w_qkv, w_out, btab, ridx, wq_bf, wo_bf, blut);
    fused_win_mha<<<2048, 1024, 0, stream>>>(x, ln_g, ln_b, b_out, wq_bf, wo_bf, blut, out);
}